// Round 11
// baseline (145.923 us; speedup 1.0000x reference)
//
#include <hip/hip_runtime.h>
#include <stdint.h>

#define NROW 256
#define NV   128000
#define NV4  (NV / 4)
#define HALF_F4 (NV4 / 2)       // 16000 float4 per half-row
#define NBIN 7680
#define NCH  8
#define BLO  0x42300000u        // bits of 44.0f
#define BSH  10
#define GCAP 4096
#define LOG2E 1.44269504088896340736f
#define TPB  1024
#define RMARG 1.005f
#define T_HI_BITS 0x42A7FFFFu   // ~83.99999 -> bin <= 7679
#define NG   2048               // select radix groups
#define TCAP 2048               // tie capacity

// ---- workspace layout (bytes) ----
#define PART_BYTES ((size_t)512 * (NBIN / 2) * 4)        // 7,864,320 (packed u16 pairs)
#define WS_PART   0
#define WS_ZQ     (PART_BYTES)                            // 256*8 f32 (2 slots/row used)
#define WS_PARAMS (WS_ZQ + (size_t)NROW * 8 * 4)
#define WS_NEEDED (WS_PARAMS + (size_t)NROW * 16)

struct RowParams { int bl; int bh; float P; int pad; };

__device__ __forceinline__ unsigned fenc(float f) {
    unsigned b = __float_as_uint(f);
    return b ^ (((unsigned)((int)b >> 31)) | 0x80000000u);
}
__device__ __forceinline__ float fdec(unsigned e) {
    unsigned m = ((int)e >= 0) ? 0xFFFFFFFFu : 0x80000000u;
    return __uint_as_float(e ^ m);
}

// monotone race key: log2(p/noise) + const = s*log2e - log2(-log2 u) + const
__device__ __forceinline__ unsigned long long race_key(float s, float u, unsigned idx) {
    float nl  = -__builtin_amdgcn_logf(u);
    float l2n = __builtin_amdgcn_logf(nl);
    float keyf = fmaf(s, LOG2E, -l2n);
    return ((unsigned long long)fenc(keyf) << 32) | (unsigned)(~idx);
}

__device__ __forceinline__ int bin_of(float s) {
    float tc = fminf(fmaxf(s + 64.0f, 44.0f), __uint_as_float(T_HI_BITS));
    return (int)((__float_as_uint(tc) - BLO) >> BSH);
}

__device__ __forceinline__ float qval(float s) {       // exp(s) * 2^-20
    return __builtin_amdgcn_exp2f(fmaf(s, LOG2E, -20.0f));
}

__device__ __forceinline__ float cmid(int b) {         // geometric-mid mass of bin b
    float tlo = __uint_as_float(BLO + ((unsigned)b << BSH));
    float thi = __uint_as_float(BLO + ((unsigned)(b + 1) << BSH));
    float tm = 0.5f * (tlo + thi);
    return __builtin_amdgcn_exp2f(fmaf(tm - 64.0f, LOG2E, -20.0f));
}

// ------- K1: integer count histogram + exact Zq (2 blocks/row, 30KB LDS) ----
__global__ __launch_bounds__(TPB)
void k1_hist(const float* __restrict__ logits, const float* __restrict__ temps,
             unsigned* __restrict__ partials, float* __restrict__ zq)
{
    __shared__ unsigned lh[NBIN];
    __shared__ float wred[16];
    const int row = blockIdx.x >> 1;
    const int sl  = blockIdx.x & 1;
    const int tid = threadIdx.x;
    for (int b = tid; b < NBIN; b += TPB) lh[b] = 0u;
    __syncthreads();
    const float invT = 1.0f / temps[row];
    const float4* __restrict__ l4 =
        (const float4*)(logits + (size_t)row * NV) + sl * HALF_F4;
    float zacc0 = 0.0f, zacc1 = 0.0f;       // dual accumulators (ILP)
    for (int v = tid; v < HALF_F4; v += TPB) {
        float4 x = l4[v];
        float xs[4] = {x.x, x.y, x.z, x.w};
        #pragma unroll
        for (int c = 0; c < 4; ++c) {
            float s = xs[c] * invT;
            atomicAdd(&lh[bin_of(s)], 1u);
            if (c & 1) zacc1 += qval(s); else zacc0 += qval(s);
        }
    }
    float zacc = zacc0 + zacc1;
    #pragma unroll
    for (int o = 32; o > 0; o >>= 1) zacc += __shfl_down(zacc, o, 64);
    if ((tid & 63) == 0) wred[tid >> 6] = zacc;
    __syncthreads();
    if (tid == 0) {
        float z = 0.0f;
        #pragma unroll
        for (int w = 0; w < TPB / 64; ++w) z += wred[w];
        zq[row * 8 + sl] = z;               // per-slice slot, no atomic, no init
    }
    unsigned* __restrict__ pc = partials + (size_t)blockIdx.x * (NBIN / 2);
    for (int pb = tid; pb < NBIN / 2; pb += TPB)
        pc[pb] = (lh[2 * pb] & 0xFFFFu) | (lh[2 * pb + 1] << 16);
}

// ---------------- K2: merge counts, bounded window [bL', bH] -----------------
__global__ __launch_bounds__(TPB)
void k2_scan(const unsigned* __restrict__ partials, const float* __restrict__ topps,
             const float* __restrict__ zq, RowParams* __restrict__ params)
{
    __shared__ float qm[NBIN];    // mass (then per-bin mass suffix)
    __shared__ float qc[NBIN];    // count (then per-bin count suffix)
    __shared__ float ct[TPB];
    __shared__ float ct2[TPB];
    __shared__ int shbH, shbL, shbLp;
    const int row = blockIdx.x, tid = threadIdx.x;
    const unsigned* __restrict__ p0 = partials + (size_t)(row * 2) * (NBIN / 2);
    const unsigned* __restrict__ p1 = p0 + (NBIN / 2);
    for (int pb = tid; pb < NBIN / 2; pb += TPB) {
        unsigned a = p0[pb], b = p1[pb];
        unsigned c0 = (a & 0xFFFFu) + (b & 0xFFFFu);
        unsigned c1 = (a >> 16) + (b >> 16);
        int b0 = 2 * pb, b1 = 2 * pb + 1;
        qc[b0] = (float)c0; qm[b0] = c0 ? (float)c0 * cmid(b0) : 0.0f;
        qc[b1] = (float)c1; qm[b1] = c1 ? (float)c1 * cmid(b1) : 0.0f;
    }
    if (tid == 0) { shbH = NBIN - 1; shbL = 0; }
    __syncthreads();

    // mass: chunk sums -> suffix scan -> per-bin suffix writeback
    float chs = 0.0f;
    if (tid < NBIN / NCH) {
        int b0 = tid * NCH;
        #pragma unroll
        for (int i = 0; i < NCH; ++i) chs += qm[b0 + i];
    }
    ct[tid] = chs;
    __syncthreads();
    float* src = ct; float* dst = ct2;
    for (int d = 1; d < TPB; d <<= 1) {
        float v = src[tid] + ((tid + d < TPB) ? src[tid + d] : 0.0f);
        dst[tid] = v;
        __syncthreads();
        float* tm = src; src = dst; dst = tm;
    }
    {
        float run = (tid + 1 < TPB) ? src[tid + 1] : 0.0f;
        if (tid < NBIN / NCH) {
            int b0 = tid * NCH;
            for (int i = NCH - 1; i >= 0; --i) { run += qm[b0 + i]; qm[b0 + i] = run; }
        }
    }
    __syncthreads();

    // counts: same machinery
    float chc = 0.0f;
    if (tid < NBIN / NCH) {
        int b0 = tid * NCH;
        #pragma unroll
        for (int i = 0; i < NCH; ++i) chc += qc[b0 + i];
    }
    ct[tid] = chc;
    __syncthreads();
    src = ct; dst = ct2;
    for (int d = 1; d < TPB; d <<= 1) {
        float v = src[tid] + ((tid + d < TPB) ? src[tid + d] : 0.0f);
        dst[tid] = v;
        __syncthreads();
        float* tm = src; src = dst; dst = tm;
    }
    {
        float run = (tid + 1 < TPB) ? src[tid + 1] : 0.0f;
        if (tid < NBIN / NCH) {
            int b0 = tid * NCH;
            for (int i = NCH - 1; i >= 0; --i) { run += qc[b0 + i]; qc[b0 + i] = run; }
        }
    }
    __syncthreads();

    const float P = topps[row] * (zq[row * 8] + zq[row * 8 + 1]);
    if (tid < NBIN / NCH) {
        int b0 = tid * NCH;
        for (int i = 0; i < NCH; ++i) {
            int b = b0 + i;
            float Sb  = qm[b];
            float Sb1 = (b + 1 < NBIN) ? qm[b + 1] : 0.0f;
            if (Sb1 * RMARG <= P) atomicMin(&shbH, b);   // bins > bH definitely kept
            if (Sb > RMARG * P)   atomicMax(&shbL, b);   // bins < bL definitely masked
        }
    }
    __syncthreads();
    const int bH = shbH;
    if (tid == 0) shbLp = bH;
    __syncthreads();
    const float target = (float)GCAP + ((bH + 1 < NBIN) ? qc[bH + 1] : 0.0f);
    const int bL = shbL;
    if (tid < NBIN / NCH) {
        int b0 = tid * NCH;
        for (int i = 0; i < NCH; ++i) {
            int b = b0 + i;
            if (b >= bL && qc[b] <= target) atomicMin(&shbLp, b);  // window fits GCAP
        }
    }
    __syncthreads();
    if (tid == 0) {
        RowParams rp; rp.bl = shbLp; rp.bh = bH; rp.P = P; rp.pad = 0;
        params[row] = rp;
    }
}

// ===== Kernel B: one block per row — race + LDS-staged window + select ======
__global__ __launch_bounds__(TPB, 4)
void kB_race_select(const float* __restrict__ logits, const float* __restrict__ temps,
                    const float* __restrict__ unoise,
                    const RowParams* __restrict__ params, int* __restrict__ out)
{
    __shared__ unsigned long long stage[GCAP];   // 32 KB window keys
    __shared__ unsigned stageU[GCAP];            // 16 KB window u
    __shared__ float ms[NG];                     //  8 KB group masses
    __shared__ float ssA[NG];                    //  8 KB scan ping
    __shared__ float ssB[NG];                    //  8 KB scan pong
    __shared__ unsigned long long tk[TCAP];      // 16 KB tie keys
    __shared__ unsigned tu[TCAP];                //  8 KB tie u
    __shared__ float wsab[16];
    __shared__ unsigned long long red_b[16];
    __shared__ unsigned lcnt;
    __shared__ float shA;
    __shared__ int sh_gstar, sh_kst;
    __shared__ unsigned sh_kmin, sh_kmax, sh_tn;
    __shared__ float sh_above;

    const int row = blockIdx.x;
    const int tid = threadIdx.x;
    if (tid == 0) {
        lcnt = 0u; sh_gstar = -1; sh_tn = 0u; sh_kst = 0;
        sh_kmin = 0xFFFFFFFFu; sh_kmax = 0u;
    }
    __syncthreads();

    const RowParams rp = params[row];
    const int bl = rp.bl, bh = rp.bh;
    const float P = rp.P;
    const float invT = 1.0f / temps[row];
    const float4* __restrict__ l4 = (const float4*)(logits + (size_t)row * NV);
    const float4* __restrict__ u4 = (const float4*)(unoise + (size_t)row * NV);
    unsigned long long mybest = 0ull;
    float sabacc = 0.0f;

    for (int v = tid; v < NV4; v += 2 * TPB) {
        int v1 = v + TPB;
        bool g1 = v1 < NV4;
        float4 x0 = l4[v];
        float4 u0 = u4[v];
        float4 x1 = l4[g1 ? v1 : v];
        float4 u1 = u4[g1 ? v1 : v];
        float xs0[4] = {x0.x, x0.y, x0.z, x0.w};
        float us0[4] = {u0.x, u0.y, u0.z, u0.w};
        float xs1[4] = {x1.x, x1.y, x1.z, x1.w};
        float us1[4] = {u1.x, u1.y, u1.z, u1.w};
        #pragma unroll
        for (int c = 0; c < 4; ++c) {
            float s = xs0[c] * invT;
            int bin = bin_of(s);
            unsigned idx = (unsigned)(v * 4 + c);
            if (bin > bh) {
                unsigned long long key = race_key(s, us0[c], idx);
                if (key > mybest) mybest = key;
                sabacc += qval(s);
            } else if (bin >= bl) {
                unsigned pos = atomicAdd(&lcnt, 1u);
                if (pos < GCAP) {
                    stage[pos] = ((unsigned long long)fenc(s) << 32) | (unsigned)(~idx);
                    stageU[pos] = __float_as_uint(us0[c]);
                }
            }
        }
        #pragma unroll
        for (int c = 0; c < 4; ++c) {
            if (g1) {
                float s = xs1[c] * invT;
                int bin = bin_of(s);
                unsigned idx = (unsigned)(v1 * 4 + c);
                if (bin > bh) {
                    unsigned long long key = race_key(s, us1[c], idx);
                    if (key > mybest) mybest = key;
                    sabacc += qval(s);
                } else if (bin >= bl) {
                    unsigned pos = atomicAdd(&lcnt, 1u);
                    if (pos < GCAP) {
                        stage[pos] = ((unsigned long long)fenc(s) << 32) | (unsigned)(~idx);
                        stageU[pos] = __float_as_uint(us1[c]);
                    }
                }
            }
        }
    }

    // reduce S_above (exact kept mass); mybest stays in-register through select
    #pragma unroll
    for (int o = 32; o > 0; o >>= 1) sabacc += __shfl_down(sabacc, o, 64);
    if ((tid & 63) == 0) wsab[tid >> 6] = sabacc;
    __syncthreads();
    if (tid == 0) {
        float sz = 0.0f;
        #pragma unroll
        for (int w = 0; w < TPB / 64; ++w) sz += wsab[w];
        shA = sz;
    }
    for (int g = tid; g < NG; g += TPB) ms[g] = 0.0f;
    __syncthreads();

    unsigned n = lcnt; if (n > GCAP) n = GCAP;
    if (n > 0) {
        // pass 1: key min/max
        unsigned kmn = 0xFFFFFFFFu, kmx = 0u;
        for (unsigned p = tid; p < n; p += TPB) {
            unsigned k = (unsigned)(stage[p] >> 32);
            kmn = min(kmn, k); kmx = max(kmx, k);
        }
        atomicMin(&sh_kmin, kmn);
        atomicMax(&sh_kmax, kmx);
        __syncthreads();
        const unsigned kmin = sh_kmin;
        const unsigned span = sh_kmax - kmin;
        const int Lb = 32 - __clz(span);            // span==0 -> 0
        const int shft = (Lb > 11) ? (Lb - 11) : 0; // groups <= 2048

        // pass 2: group mass histogram
        for (unsigned p = tid; p < n; p += TPB) {
            unsigned key = (unsigned)(stage[p] >> 32);
            atomicAdd(&ms[(key - kmin) >> shft], qval(fdec(key)));
        }
        __syncthreads();

        // suffix-inclusive scan over groups
        for (int g = tid; g < NG; g += TPB) ssA[g] = ms[g];
        __syncthreads();
        float* src = ssA; float* dst = ssB;
        for (int d = 1; d < NG; d <<= 1) {
            for (int g = tid; g < NG; g += TPB)
                dst[g] = src[g] + ((g + d < NG) ? src[g + d] : 0.0f);
            __syncthreads();
            float* tm = src; src = dst; dst = tm;
        }
        const float A = shA;
        for (int g = tid; g < NG; g += TPB) {
            float SI  = src[g];
            float SI1 = (g + 1 < NG) ? src[g + 1] : 0.0f;
            if (A + SI > P && A + SI1 <= P) atomicMax(&sh_gstar, g);
        }
        __syncthreads();
        const int gstar = sh_gstar;
        if (tid == 0)
            sh_above = A + ((gstar >= 0 && gstar + 1 < NG) ? src[gstar + 1] : 0.0f);

        // pass 3: kept groups race; crossing group stages ties
        for (unsigned p = tid; p < n; p += TPB) {
            unsigned long long e = stage[p];
            unsigned key = (unsigned)(e >> 32);
            int g = (int)((key - kmin) >> shft);
            if (gstar < 0 || g > gstar) {
                unsigned idx = ~(unsigned)(e & 0xFFFFFFFFull);
                unsigned long long k2 =
                    race_key(fdec(key), __uint_as_float(stageU[p]), idx);
                if (k2 > mybest) mybest = k2;
            } else if (g == gstar) {
                unsigned t = atomicAdd(&sh_tn, 1u);
                if (t < TCAP) { tk[t] = e; tu[t] = stageU[p]; }
            }
        }
        __syncthreads();
        unsigned tn = sh_tn; if (tn > TCAP) tn = TCAP;
        if (gstar >= 0 && tn > 0u) {
            int N2 = 64; while (N2 < (int)tn) N2 <<= 1;
            for (int i = tid; i < N2; i += TPB)
                if (i >= (int)tn) { tk[i] = 0ull; tu[i] = 0u; }
            __syncthreads();
            // bitonic sort descending on (key, ~idx), payload tu
            for (int k = 2; k <= N2; k <<= 1) {
                for (int j2 = k >> 1; j2 > 0; j2 >>= 1) {
                    for (int i = tid; i < N2; i += TPB) {
                        int ixj = i ^ j2;
                        if (ixj > i) {
                            unsigned long long a = tk[i], b = tk[ixj];
                            if (((i & k) == 0) ? (a < b) : (a > b)) {
                                tk[i] = b; tk[ixj] = a;
                                unsigned ut = tu[i]; tu[i] = tu[ixj]; tu[ixj] = ut;
                            }
                        }
                    }
                    __syncthreads();
                }
            }
            // inclusive prefix scan of tie masses
            for (int i = tid; i < N2; i += TPB)
                ssA[i] = (i < (int)tn) ? qval(fdec((unsigned)(tk[i] >> 32))) : 0.0f;
            __syncthreads();
            float* s1 = ssA; float* s2 = ssB;
            for (int d = 1; d < N2; d <<= 1) {
                for (int i = tid; i < N2; i += TPB)
                    s2[i] = s1[i] + ((i >= d) ? s1[i - d] : 0.0f);
                __syncthreads();
                float* tm = s1; s1 = s2; s2 = tm;
            }
            const float above = sh_above;
            for (int i = tid; i < (int)tn; i += TPB) {
                float excl = above + ((i == 0) ? 0.0f : s1[i - 1]);
                if (excl <= P) atomicMax(&sh_kst, i + 1);
            }
            __syncthreads();
            const int kst = sh_kst;
            for (int i = tid; i < kst; i += TPB) {
                unsigned idx = ~(unsigned)(tk[i] & 0xFFFFFFFFull);
                unsigned long long k2 =
                    race_key(fdec((unsigned)(tk[i] >> 32)), __uint_as_float(tu[i]), idx);
                if (k2 > mybest) mybest = k2;
            }
            __syncthreads();
        }
    }

    // final winner reduce
    #pragma unroll
    for (int o = 32; o > 0; o >>= 1) {
        unsigned long long other = __shfl_down(mybest, o, 64);
        if (other > mybest) mybest = other;
    }
    if ((tid & 63) == 0) red_b[tid >> 6] = mybest;
    __syncthreads();
    if (tid == 0) {
        unsigned long long m2 = red_b[0];
        #pragma unroll
        for (int w = 1; w < TPB / 64; ++w) if (red_b[w] > m2) m2 = red_b[w];
        out[row] = (int)(~(unsigned)(m2 & 0xFFFFFFFFull));
    }
}

// =================== fallback: proven round-1 single kernel ==================
#define ONT 1024
__global__ __launch_bounds__(ONT, 1)
void sampler_fallback(const float* __restrict__ logits,
                      const float* __restrict__ temps,
                      const float* __restrict__ topps,
                      const float* __restrict__ unoise,
                      int* __restrict__ out)
{
    __shared__ float qmass[NBIN];
    __shared__ float ct[ONT];
    __shared__ float ct2[ONT];
    __shared__ unsigned long long gkeys[GCAP];
    __shared__ float sa[GCAP];
    __shared__ float sb[GCAP];
    __shared__ float wred[16];
    __shared__ unsigned long long sh_cross;
    __shared__ unsigned long long sh_best;
    __shared__ unsigned int gcnt;
    __shared__ int sh_bstar;
    __shared__ float sh_A;
    __shared__ float sh_m;
    __shared__ float sh_Zq;
    __shared__ int sh_kstar;

    const int row = blockIdx.x;
    const int tid = threadIdx.x;
    const float* __restrict__ lrow = logits + (size_t)row * NV;
    const float* __restrict__ urow = unoise + (size_t)row * NV;
    const float invT = 1.0f / temps[row];
    const float topp = topps[row];

    for (int b = tid; b < NBIN; b += ONT) qmass[b] = 0.0f;
    if (tid == 0) { sh_cross = 0ull; sh_best = 0ull; gcnt = 0u; sh_kstar = 0; sh_bstar = 0; sh_A = 0.0f; }
    __syncthreads();

    const float4* __restrict__ l4 = (const float4*)lrow;
    float mloc = -3.402823466e38f;
    const float qscale = 9.5367431640625e-07f;
    for (int v = tid; v < NV4; v += ONT) {
        float4 x = l4[v];
        float xs[4] = {x.x, x.y, x.z, x.w};
        #pragma unroll
        for (int c = 0; c < 4; ++c) {
            float s = xs[c] * invT;
            mloc = fmaxf(mloc, s);
            float q = __expf(s) * qscale;
            float t = fminf(fmaxf(s + 64.0f, 44.0f), 84.0f);
            int bin = (int)((__float_as_uint(t) - BLO) >> BSH);
            bin = min(bin, NBIN - 1);
            atomicAdd(&qmass[bin], q);
        }
    }
    #pragma unroll
    for (int o = 32; o > 0; o >>= 1) mloc = fmaxf(mloc, __shfl_down(mloc, o, 64));
    if ((tid & 63) == 0) wred[tid >> 6] = mloc;
    __syncthreads();
    if (tid < 16) {
        float vv = wred[tid];
        #pragma unroll
        for (int o = 8; o > 0; o >>= 1) vv = fmaxf(vv, __shfl_down(vv, o, 16));
        if (tid == 0) sh_m = vv;
    }
    __syncthreads();
    const float m = sh_m;

    const int b0 = tid * NCH;
    float chs = 0.0f;
    #pragma unroll
    for (int i2 = 0; i2 < NCH; ++i2) {
        int b = b0 + i2;
        if (b < NBIN) chs += qmass[b];
    }
    ct[tid] = chs;
    __syncthreads();
    float* src = ct; float* dst = ct2;
    for (int d = 1; d < ONT; d <<= 1) {
        float val = src[tid] + ((tid + d < ONT) ? src[tid + d] : 0.0f);
        dst[tid] = val;
        __syncthreads();
        float* tm = src; src = dst; dst = tm;
    }
    const float Zq = src[0];
    const float P = topp * Zq;
    {
        float mine = src[tid];
        float nxt = (tid + 1 < ONT) ? src[tid + 1] : 0.0f;
        if (mine > P && nxt <= P)
            atomicMax(&sh_cross, ((unsigned long long)(tid + 1) << 32));
    }
    __syncthreads();
    if (tid == 0) {
        sh_Zq = Zq;
        if (sh_cross == 0ull) { sh_bstar = -1000000; sh_A = 0.0f; }
        else {
            int cstar = (int)(sh_cross >> 32) - 1;
            float run = (cstar + 1 < ONT) ? src[cstar + 1] : 0.0f;
            int bst = -1; float abv = run;
            for (int i2 = NCH - 1; i2 >= 0; --i2) {
                int b = cstar * NCH + i2;
                if (b >= NBIN) continue;
                float inc = qmass[b];
                if (run <= P && run + inc > P) { bst = b; abv = run; break; }
                run += inc;
            }
            if (bst < 0) { bst = cstar * NCH; abv = run; }
            sh_bstar = bst;
            float A = abv;
            if (bst + 1 < NBIN) A -= qmass[bst + 1];
            if (A < 0.0f) A = 0.0f;
            sh_A = A;
        }
    }
    __syncthreads();

    const int bstar = sh_bstar;
    const float Zrow = sh_Zq * 1048576.0f * __expf(-m);
    const float invZrow = 1.0f / Zrow;

    const float4* __restrict__ u4 = (const float4*)urow;
    unsigned long long mybest = 0ull;
    for (int v = tid; v < NV4; v += ONT) {
        float4 x = l4[v];
        float4 uu = u4[v];
        float xs[4] = {x.x, x.y, x.z, x.w};
        float us[4] = {uu.x, uu.y, uu.z, uu.w};
        #pragma unroll
        for (int c = 0; c < 4; ++c) {
            float s = xs[c] * invT;
            float t = fminf(fmaxf(s + 64.0f, 44.0f), 84.0f);
            int bin = (int)((__float_as_uint(t) - BLO) >> BSH);
            bin = min(bin, NBIN - 1);
            if (bin >= bstar + 2) {
                float e = __expf(s - m);
                float noise = fmaxf(-__logf(us[c]), 1e-10f);
                float r = __fdividef(e * invZrow, noise);
                int i = v * 4 + c;
                unsigned long long key = ((unsigned long long)__float_as_uint(r) << 32)
                                       | (unsigned long long)(0xFFFFFFFFu - (unsigned)i);
                if (key > mybest) mybest = key;
            } else if (bin >= bstar - 1) {
                float e = __expf(s - m);
                float p = e / Zrow;
                int i = v * 4 + c;
                unsigned int pos = atomicAdd(&gcnt, 1u);
                if (pos < GCAP)
                    gkeys[pos] = ((unsigned long long)__float_as_uint(p) << 32)
                               | (unsigned long long)(0xFFFFFFFFu - (unsigned)i);
            }
        }
    }
    atomicMax(&sh_best, mybest);
    __syncthreads();

    unsigned int ngu = gcnt; if (ngu > GCAP) ngu = GCAP;
    const int ng = (int)ngu;
    for (int i = tid; i < GCAP; i += ONT) if (i >= ng) gkeys[i] = 0ull;
    __syncthreads();
    if (ng > 0) {
        for (int k = 2; k <= GCAP; k <<= 1) {
            for (int j = k >> 1; j > 0; j >>= 1) {
                for (int i = tid; i < GCAP; i += ONT) {
                    int ixj = i ^ j;
                    if (ixj > i) {
                        unsigned long long a = gkeys[i], b = gkeys[ixj];
                        bool up = ((i & k) == 0);
                        bool sw = up ? (a < b) : (a > b);
                        if (sw) { gkeys[i] = b; gkeys[ixj] = a; }
                    }
                }
                __syncthreads();
            }
        }
        for (int i = tid; i < GCAP; i += ONT)
            sa[i] = __uint_as_float((unsigned)(gkeys[i] >> 32));
        __syncthreads();
        float* ssrc = sa; float* sdst = sb;
        for (int d = 1; d < GCAP; d <<= 1) {
            for (int i = tid; i < GCAP; i += ONT)
                sdst[i] = ssrc[i] + ((i >= d) ? ssrc[i - d] : 0.0f);
            __syncthreads();
            float* tm = ssrc; ssrc = sdst; sdst = tm;
        }
        const float A_p = sh_A / sh_Zq;
        for (int i = tid; i < GCAP; i += ONT) {
            if (i < ng) {
                float excl = (i == 0) ? A_p : (A_p + ssrc[i - 1]);
                if (excl <= topp) atomicMax(&sh_kstar, i + 1);
            }
        }
        __syncthreads();
        const int kst = sh_kstar;
        unsigned long long gb = 0ull;
        for (int i = tid; i < kst; i += ONT) {
            unsigned long long key = gkeys[i];
            unsigned int idx = 0xFFFFFFFFu - (unsigned)(key & 0xFFFFFFFFull);
            float p = __uint_as_float((unsigned)(key >> 32));
            float u = urow[idx];
            float noise = fmaxf(-__logf(u), 1e-10f);
            float r = __fdividef(p, noise);
            unsigned long long k2 = ((unsigned long long)__float_as_uint(r) << 32)
                                  | (unsigned long long)(0xFFFFFFFFu - idx);
            if (k2 > gb) gb = k2;
        }
        atomicMax(&sh_best, gb);
        __syncthreads();
    }
    if (tid == 0) {
        unsigned long long kk = sh_best;
        out[row] = (int)(0xFFFFFFFFu - (unsigned)(kk & 0xFFFFFFFFull));
    }
}

extern "C" void kernel_launch(void* const* d_in, const int* in_sizes, int n_in,
                              void* d_out, int out_size, void* d_ws, size_t ws_size,
                              hipStream_t stream) {
    const float* logits = (const float*)d_in[0];
    const float* temps  = (const float*)d_in[1];
    const float* topps  = (const float*)d_in[2];
    const float* unoise = (const float*)d_in[3];
    int* out = (int*)d_out;

    if (ws_size < WS_NEEDED) {
        hipLaunchKernelGGL(sampler_fallback, dim3(NROW), dim3(ONT), 0, stream,
                           logits, temps, topps, unoise, out);
        return;
    }

    char* ws = (char*)d_ws;
    unsigned* partials = (unsigned*)(ws + WS_PART);
    float* zq   = (float*)(ws + WS_ZQ);
    RowParams* params = (RowParams*)(ws + WS_PARAMS);

    hipLaunchKernelGGL(k1_hist, dim3(NROW * 2), dim3(TPB), 0, stream,
                       logits, temps, partials, zq);
    hipLaunchKernelGGL(k2_scan, dim3(NROW), dim3(TPB), 0, stream,
                       partials, topps, zq, params);
    hipLaunchKernelGGL(kB_race_select, dim3(NROW), dim3(TPB), 0, stream,
                       logits, temps, unoise, params, out);
}

// Round 12
// 91.373 us; speedup vs baseline: 1.5970x; 1.5970x over previous
//
#include <hip/hip_runtime.h>
#include <stdint.h>

#define NROW 256
#define NV   128000
#define NV4  (NV / 4)
#define GCAP 4096
#define LOG2E 1.44269504088896340736f
#define TPB  1024
#define NG   2048               // select radix groups
#define TCAP 2048               // tie capacity

__device__ __forceinline__ unsigned fenc(float f) {
    unsigned b = __float_as_uint(f);
    return b ^ (((unsigned)((int)b >> 31)) | 0x80000000u);
}
__device__ __forceinline__ float fdec(unsigned e) {
    unsigned m = ((int)e >= 0) ? 0xFFFFFFFFu : 0x80000000u;
    return __uint_as_float(e ^ m);
}

// monotone race key: log2(p/noise) + const = s*log2e - log2(-log2 u) + const
__device__ __forceinline__ unsigned long long race_key(float s, float u, unsigned idx) {
    float nl  = -__builtin_amdgcn_logf(u);
    float l2n = __builtin_amdgcn_logf(nl);
    float keyf = fmaf(s, LOG2E, -l2n);
    return ((unsigned long long)fenc(keyf) << 32) | (unsigned)(~idx);
}

__device__ __forceinline__ float qval(float s) {       // exp(s) * 2^-20
    return __builtin_amdgcn_exp2f(fmaf(s, LOG2E, -20.0f));
}

// Acklam inverse normal CDF (abs err ~1e-7 in z; window margin >> this)
__device__ float phi_inv(float p) {
    const float a1=-3.969683028665376e+01f, a2=2.209460984245205e+02f,
                a3=-2.759285104469687e+02f, a4=1.383577518672690e+02f,
                a5=-3.066479806614716e+01f, a6=2.506628277459239e+00f;
    const float b1=-5.447609879822406e+01f, b2=1.615858368580409e+02f,
                b3=-1.556989798598866e+02f, b4=6.680131188771972e+01f,
                b5=-1.328068155288572e+01f;
    const float c1=-7.784894002430293e-03f, c2=-3.223964580411365e-01f,
                c3=-2.400758277161838e+00f, c4=-2.549732539343734e+00f,
                c5=4.374664141464968e+00f,  c6=2.938163982698783e+00f;
    const float d1=7.784695709041462e-03f, d2=3.224671290700398e-01f,
                d3=2.445134137142996e+00f, d4=3.754408661907416e+00f;
    const float plow = 0.02425f, phigh = 1.0f - plow;
    float q, r, x;
    if (p < plow) {
        q = sqrtf(-2.0f * logf(p));
        x = (((((c1*q+c2)*q+c3)*q+c4)*q+c5)*q+c6) /
            ((((d1*q+d2)*q+d3)*q+d4)*q+1.0f);
    } else if (p <= phigh) {
        q = p - 0.5f; r = q * q;
        x = (((((a1*r+a2)*r+a3)*r+a4)*r+a5)*r+a6)*q /
            (((((b1*r+b2)*r+b3)*r+b4)*r+b5)*r+1.0f);
    } else {
        q = sqrtf(-2.0f * logf(1.0f - p));
        x = -(((((c1*q+c2)*q+c3)*q+c4)*q+c5)*q+c6) /
             ((((d1*q+d2)*q+d3)*q+d4)*q+1.0f);
    }
    return x;
}

// ===== single kernel: Zq pass + analytic-window race/stage (verified) + select
__global__ __launch_bounds__(TPB, 4)
void sampler_all(const float* __restrict__ logits, const float* __restrict__ temps,
                 const float* __restrict__ topps, const float* __restrict__ unoise,
                 int* __restrict__ out)
{
    __shared__ unsigned long long stage[GCAP];   // 32 KB
    __shared__ unsigned stageU[GCAP];            // 16 KB
    __shared__ float ms[NG];                     //  8 KB
    __shared__ float ssA[NG];                    //  8 KB
    __shared__ float ssB[NG];                    //  8 KB
    __shared__ unsigned long long tk[TCAP];      // 16 KB
    __shared__ unsigned tu[TCAP];                //  8 KB
    __shared__ float wred[16];
    __shared__ unsigned long long red_b[16];
    __shared__ unsigned lcnt;
    __shared__ float shP, shA, shWin, sh_sLo, sh_sHi, sh_zl, sh_zh;
    __shared__ int sh_ok;
    __shared__ int sh_gstar, sh_kst;
    __shared__ unsigned sh_kmin, sh_kmax, sh_tn;
    __shared__ float sh_above;

    const int row = blockIdx.x;
    const int tid = threadIdx.x;
    const float invT = 1.0f / temps[row];
    const float topp = topps[row];
    const float4* __restrict__ l4 = (const float4*)(logits + (size_t)row * NV);
    const float4* __restrict__ u4 = (const float4*)(unoise + (size_t)row * NV);

    // ---------------- P1: Zq (stream logits) --------------------------------
    float za0 = 0.0f, za1 = 0.0f;
    for (int v = tid; v < NV4; v += 2 * TPB) {
        int v1 = v + TPB;
        bool g1 = v1 < NV4;
        float4 x0 = l4[v];
        float4 x1 = l4[g1 ? v1 : v];
        float xs0[4] = {x0.x, x0.y, x0.z, x0.w};
        float xs1[4] = {x1.x, x1.y, x1.z, x1.w};
        #pragma unroll
        for (int c = 0; c < 4; ++c) {
            float s = xs0[c] * invT;
            if (c & 1) za1 += qval(s); else za0 += qval(s);
        }
        #pragma unroll
        for (int c = 0; c < 4; ++c) {
            if (g1) {
                float s = xs1[c] * invT;
                if (c & 1) za1 += qval(s); else za0 += qval(s);
            }
        }
    }
    float zacc = za0 + za1;
    #pragma unroll
    for (int o = 32; o > 0; o >>= 1) zacc += __shfl_down(zacc, o, 64);
    if ((tid & 63) == 0) wred[tid >> 6] = zacc;
    __syncthreads();
    if (tid == 0) {
        float Zq = 0.0f;
        #pragma unroll
        for (int w = 0; w < TPB / 64; ++w) Zq += wred[w];
        shP = topp * Zq;
        // analytic window: mass-cut at z0 = sigma + PhicInv(topp); count-based bracket
        float sigma = invT;
        float tc = fminf(fmaxf(topp, 1e-7f), 1.0f - 1e-7f);
        float z0 = sigma - phi_inv(tc);               // PhicInv(p) = -PhiInv(p)
        float cdf0 = 0.5f * erfcf(-z0 * 0.70710678f); // Phi(z0)
        const float WH = 1600.0f / 128000.0f;
        float cdfl = cdf0 - WH, cdfh = cdf0 + WH;
        float zl = (cdfl <= 1e-7f) ? -1e30f : phi_inv(cdfl);
        float zh = (cdfh >= 1.0f - 1e-7f) ? 1e30f : phi_inv(cdfh);
        sh_zl = zl; sh_zh = zh;
        sh_sLo = sigma * zl; sh_sHi = sigma * zh;
        sh_ok = 0;
    }
    __syncthreads();
    const float P = shP;
    const float sigma = invT;

    // ---------------- P2: race + stage window, verify + retry ---------------
    unsigned long long mybest = 0ull;
    for (int attempt = 0; attempt < 32; ++attempt) {
        if (tid == 0) lcnt = 0u;
        __syncthreads();
        const float sLo = sh_sLo, sHi = sh_sHi;
        mybest = 0ull;
        float aacc = 0.0f, wacc = 0.0f;
        for (int v = tid; v < NV4; v += 2 * TPB) {
            int v1 = v + TPB;
            bool g1 = v1 < NV4;
            float4 x0 = l4[v];
            float4 u0 = u4[v];
            float4 x1 = l4[g1 ? v1 : v];
            float4 u1 = u4[g1 ? v1 : v];
            float xs0[4] = {x0.x, x0.y, x0.z, x0.w};
            float us0[4] = {u0.x, u0.y, u0.z, u0.w};
            float xs1[4] = {x1.x, x1.y, x1.z, x1.w};
            float us1[4] = {u1.x, u1.y, u1.z, u1.w};
            #pragma unroll
            for (int c = 0; c < 4; ++c) {
                float s = xs0[c] * invT;
                unsigned idx = (unsigned)(v * 4 + c);
                if (s >= sHi) {
                    unsigned long long key = race_key(s, us0[c], idx);
                    if (key > mybest) mybest = key;
                    aacc += qval(s);
                } else if (s >= sLo) {
                    wacc += qval(s);
                    unsigned pos = atomicAdd(&lcnt, 1u);
                    if (pos < GCAP) {
                        stage[pos] = ((unsigned long long)fenc(s) << 32) | (unsigned)(~idx);
                        stageU[pos] = __float_as_uint(us0[c]);
                    }
                }
            }
            #pragma unroll
            for (int c = 0; c < 4; ++c) {
                if (g1) {
                    float s = xs1[c] * invT;
                    unsigned idx = (unsigned)(v1 * 4 + c);
                    if (s >= sHi) {
                        unsigned long long key = race_key(s, us1[c], idx);
                        if (key > mybest) mybest = key;
                        aacc += qval(s);
                    } else if (s >= sLo) {
                        wacc += qval(s);
                        unsigned pos = atomicAdd(&lcnt, 1u);
                        if (pos < GCAP) {
                            stage[pos] = ((unsigned long long)fenc(s) << 32) | (unsigned)(~idx);
                            stageU[pos] = __float_as_uint(us1[c]);
                        }
                    }
                }
            }
        }
        // reduce A then winmass (reuse wred)
        #pragma unroll
        for (int o = 32; o > 0; o >>= 1) aacc += __shfl_down(aacc, o, 64);
        if ((tid & 63) == 0) wred[tid >> 6] = aacc;
        __syncthreads();
        if (tid == 0) {
            float sA = 0.0f;
            #pragma unroll
            for (int w = 0; w < TPB / 64; ++w) sA += wred[w];
            shA = sA;
        }
        __syncthreads();
        #pragma unroll
        for (int o = 32; o > 0; o >>= 1) wacc += __shfl_down(wacc, o, 64);
        if ((tid & 63) == 0) wred[tid >> 6] = wacc;
        __syncthreads();
        if (tid == 0) {
            float sW = 0.0f;
            #pragma unroll
            for (int w = 0; w < TPB / 64; ++w) sW += wred[w];
            shWin = sW;
            unsigned n = lcnt;
            float A = shA;
            bool okhi = (A <= P);
            bool okn  = (n <= GCAP);
            bool oklo = (A + sW > P) || (sh_zl <= -1e29f);
            if (okhi && okn && oklo) sh_ok = 1;
            else {
                float zl = sh_zl, zh = sh_zh;
                float width = zh - zl;
                if (!(width > 0.25f)) width = 0.25f;
                if (width > 8.0f) width = 8.0f;
                if (!okhi)      { zl = zh; zh = zh + 2.0f * width; }   // cut above window
                else if (!okn)  { zl = (zl > zh - 6.0f) ? 0.5f * (zl + zh) : (zh - 6.0f); }
                else            { zh = zl; zl = zl - 2.0f * width; }   // cut below window
                sh_zl = zl; sh_zh = zh;
                sh_sLo = sigma * zl; sh_sHi = sigma * zh;
            }
        }
        __syncthreads();
        if (sh_ok) break;
    }

    // ---------------- P3: select on window (proven round-11 machinery) ------
    if (tid == 0) {
        sh_gstar = -1; sh_tn = 0u; sh_kst = 0;
        sh_kmin = 0xFFFFFFFFu; sh_kmax = 0u;
    }
    for (int g = tid; g < NG; g += TPB) ms[g] = 0.0f;
    __syncthreads();

    unsigned n = lcnt; if (n > GCAP) n = GCAP;
    if (n > 0) {
        unsigned kmn = 0xFFFFFFFFu, kmx = 0u;
        for (unsigned p = tid; p < n; p += TPB) {
            unsigned k = (unsigned)(stage[p] >> 32);
            kmn = min(kmn, k); kmx = max(kmx, k);
        }
        atomicMin(&sh_kmin, kmn);
        atomicMax(&sh_kmax, kmx);
        __syncthreads();
        const unsigned kmin = sh_kmin;
        const unsigned span = sh_kmax - kmin;
        const int Lb = 32 - __clz(span);            // span==0 -> 0
        const int shft = (Lb > 11) ? (Lb - 11) : 0; // groups <= 2048

        for (unsigned p = tid; p < n; p += TPB) {
            unsigned key = (unsigned)(stage[p] >> 32);
            atomicAdd(&ms[(key - kmin) >> shft], qval(fdec(key)));
        }
        __syncthreads();

        for (int g = tid; g < NG; g += TPB) ssA[g] = ms[g];
        __syncthreads();
        float* src = ssA; float* dst = ssB;
        for (int d = 1; d < NG; d <<= 1) {
            for (int g = tid; g < NG; g += TPB)
                dst[g] = src[g] + ((g + d < NG) ? src[g + d] : 0.0f);
            __syncthreads();
            float* tm = src; src = dst; dst = tm;
        }
        const float A = shA;
        for (int g = tid; g < NG; g += TPB) {
            float SI  = src[g];
            float SI1 = (g + 1 < NG) ? src[g + 1] : 0.0f;
            if (A + SI > P && A + SI1 <= P) atomicMax(&sh_gstar, g);
        }
        __syncthreads();
        const int gstar = sh_gstar;
        if (tid == 0)
            sh_above = A + ((gstar >= 0 && gstar + 1 < NG) ? src[gstar + 1] : 0.0f);

        for (unsigned p = tid; p < n; p += TPB) {
            unsigned long long e = stage[p];
            unsigned key = (unsigned)(e >> 32);
            int g = (int)((key - kmin) >> shft);
            if (gstar < 0 || g > gstar) {
                unsigned idx = ~(unsigned)(e & 0xFFFFFFFFull);
                unsigned long long k2 =
                    race_key(fdec(key), __uint_as_float(stageU[p]), idx);
                if (k2 > mybest) mybest = k2;
            } else if (g == gstar) {
                unsigned t = atomicAdd(&sh_tn, 1u);
                if (t < TCAP) { tk[t] = e; tu[t] = stageU[p]; }
            }
        }
        __syncthreads();
        unsigned tn = sh_tn; if (tn > TCAP) tn = TCAP;
        if (gstar >= 0 && tn > 0u) {
            int N2 = 64; while (N2 < (int)tn) N2 <<= 1;
            for (int i = tid; i < N2; i += TPB)
                if (i >= (int)tn) { tk[i] = 0ull; tu[i] = 0u; }
            __syncthreads();
            for (int k = 2; k <= N2; k <<= 1) {
                for (int j2 = k >> 1; j2 > 0; j2 >>= 1) {
                    for (int i = tid; i < N2; i += TPB) {
                        int ixj = i ^ j2;
                        if (ixj > i) {
                            unsigned long long a = tk[i], b = tk[ixj];
                            if (((i & k) == 0) ? (a < b) : (a > b)) {
                                tk[i] = b; tk[ixj] = a;
                                unsigned ut = tu[i]; tu[i] = tu[ixj]; tu[ixj] = ut;
                            }
                        }
                    }
                    __syncthreads();
                }
            }
            for (int i = tid; i < N2; i += TPB)
                ssA[i] = (i < (int)tn) ? qval(fdec((unsigned)(tk[i] >> 32))) : 0.0f;
            __syncthreads();
            float* s1 = ssA; float* s2 = ssB;
            for (int d = 1; d < N2; d <<= 1) {
                for (int i = tid; i < N2; i += TPB)
                    s2[i] = s1[i] + ((i >= d) ? s1[i - d] : 0.0f);
                __syncthreads();
                float* tm = s1; s1 = s2; s2 = tm;
            }
            const float above = sh_above;
            for (int i = tid; i < (int)tn; i += TPB) {
                float excl = above + ((i == 0) ? 0.0f : s1[i - 1]);
                if (excl <= P) atomicMax(&sh_kst, i + 1);
            }
            __syncthreads();
            const int kst = sh_kst;
            for (int i = tid; i < kst; i += TPB) {
                unsigned idx = ~(unsigned)(tk[i] & 0xFFFFFFFFull);
                unsigned long long k2 =
                    race_key(fdec((unsigned)(tk[i] >> 32)), __uint_as_float(tu[i]), idx);
                if (k2 > mybest) mybest = k2;
            }
            __syncthreads();
        }
    }

    // final winner reduce
    #pragma unroll
    for (int o = 32; o > 0; o >>= 1) {
        unsigned long long other = __shfl_down(mybest, o, 64);
        if (other > mybest) mybest = other;
    }
    if ((tid & 63) == 0) red_b[tid >> 6] = mybest;
    __syncthreads();
    if (tid == 0) {
        unsigned long long m2 = red_b[0];
        #pragma unroll
        for (int w = 1; w < TPB / 64; ++w) if (red_b[w] > m2) m2 = red_b[w];
        out[row] = (int)(~(unsigned)(m2 & 0xFFFFFFFFull));
    }
}

extern "C" void kernel_launch(void* const* d_in, const int* in_sizes, int n_in,
                              void* d_out, int out_size, void* d_ws, size_t ws_size,
                              hipStream_t stream) {
    const float* logits = (const float*)d_in[0];
    const float* temps  = (const float*)d_in[1];
    const float* topps  = (const float*)d_in[2];
    const float* unoise = (const float*)d_in[3];
    int* out = (int*)d_out;
    hipLaunchKernelGGL(sampler_all, dim3(NROW), dim3(TPB), 0, stream,
                       logits, temps, topps, unoise, out);
}

// Round 13
// 73.949 us; speedup vs baseline: 1.9733x; 1.2356x over previous
//
#include <hip/hip_runtime.h>
#include <stdint.h>

#define NROW 256
#define NV   128000
#define NV4  (NV / 4)
#define GCAP 4096
#define LOG2E 1.44269504088896340736f
#define TPB  1024
#define NG   2048               // select radix groups
#define TCAP 2048               // tie capacity

__device__ __forceinline__ unsigned fenc(float f) {
    unsigned b = __float_as_uint(f);
    return b ^ (((unsigned)((int)b >> 31)) | 0x80000000u);
}
__device__ __forceinline__ float fdec(unsigned e) {
    unsigned m = ((int)e >= 0) ? 0xFFFFFFFFu : 0x80000000u;
    return __uint_as_float(e ^ m);
}

// monotone race key: log2(p/noise) + const = s*log2e - log2(-log2 u) + const
__device__ __forceinline__ unsigned long long race_key(float s, float u, unsigned idx) {
    float nl  = -__builtin_amdgcn_logf(u);
    float l2n = __builtin_amdgcn_logf(nl);
    float keyf = fmaf(s, LOG2E, -l2n);
    return ((unsigned long long)fenc(keyf) << 32) | (unsigned)(~idx);
}

__device__ __forceinline__ float qval(float s) {       // exp(s) * 2^-20
    return __builtin_amdgcn_exp2f(fmaf(s, LOG2E, -20.0f));
}

// Acklam inverse normal CDF (abs err ~1e-7 in z; window margin >> this)
__device__ float phi_inv(float p) {
    const float a1=-3.969683028665376e+01f, a2=2.209460984245205e+02f,
                a3=-2.759285104469687e+02f, a4=1.383577518672690e+02f,
                a5=-3.066479806614716e+01f, a6=2.506628277459239e+00f;
    const float b1=-5.447609879822406e+01f, b2=1.615858368580409e+02f,
                b3=-1.556989798598866e+02f, b4=6.680131188771972e+01f,
                b5=-1.328068155288572e+01f;
    const float c1=-7.784894002430293e-03f, c2=-3.223964580411365e-01f,
                c3=-2.400758277161838e+00f, c4=-2.549732539343734e+00f,
                c5=4.374664141464968e+00f,  c6=2.938163982698783e+00f;
    const float d1=7.784695709041462e-03f, d2=3.224671290700398e-01f,
                d3=2.445134137142996e+00f, d4=3.754408661907416e+00f;
    const float plow = 0.02425f, phigh = 1.0f - plow;
    float q, r, x;
    if (p < plow) {
        q = sqrtf(-2.0f * logf(p));
        x = (((((c1*q+c2)*q+c3)*q+c4)*q+c5)*q+c6) /
            ((((d1*q+d2)*q+d3)*q+d4)*q+1.0f);
    } else if (p <= phigh) {
        q = p - 0.5f; r = q * q;
        x = (((((a1*r+a2)*r+a3)*r+a4)*r+a5)*r+a6)*q /
            (((((b1*r+b2)*r+b3)*r+b4)*r+b5)*r+1.0f);
    } else {
        q = sqrtf(-2.0f * logf(1.0f - p));
        x = -(((((c1*q+c2)*q+c3)*q+c4)*q+c5)*q+c6) /
             ((((d1*q+d2)*q+d3)*q+d4)*q+1.0f);
    }
    return x;
}

// == single kernel, single stream pass: A/W/B buckets + race + stage + select
__global__ __launch_bounds__(TPB, 4)
void sampler_all(const float* __restrict__ logits, const float* __restrict__ temps,
                 const float* __restrict__ topps, const float* __restrict__ unoise,
                 int* __restrict__ out)
{
    __shared__ unsigned long long stage[GCAP];   // 32 KB
    __shared__ unsigned stageU[GCAP];            // 16 KB
    __shared__ float ms[NG];                     //  8 KB
    __shared__ float ssA[NG];                    //  8 KB
    __shared__ float ssB[NG];                    //  8 KB
    __shared__ unsigned long long tk[TCAP];      // 16 KB
    __shared__ unsigned tu[TCAP];                //  8 KB
    __shared__ float wred[16];
    __shared__ unsigned long long red_b[16];
    __shared__ unsigned lcnt;
    __shared__ float shP, shA, sh_sLo, sh_sHi, sh_zl, sh_zh;
    __shared__ int sh_ok;
    __shared__ int sh_gstar, sh_kst;
    __shared__ unsigned sh_kmin, sh_kmax, sh_tn;
    __shared__ float sh_above;

    const int row = blockIdx.x;
    const int tid = threadIdx.x;
    const float invT = 1.0f / temps[row];
    const float topp = topps[row];
    const float4* __restrict__ l4 = (const float4*)(logits + (size_t)row * NV);
    const float4* __restrict__ u4 = (const float4*)(unoise + (size_t)row * NV);

    // window init (depends only on sigma, topp — NOT on Zq)
    if (tid == 0) {
        float sigma = invT;
        float tc = fminf(fmaxf(topp, 1e-7f), 1.0f - 1e-7f);
        float z0 = sigma - phi_inv(tc);               // mass-cut position
        float cdf0 = 0.5f * erfcf(-z0 * 0.70710678f); // Phi(z0)
        const float WH = 1600.0f / 128000.0f;
        float cdfl = cdf0 - WH, cdfh = cdf0 + WH;
        float zl = (cdfl <= 1e-7f) ? -1e30f : phi_inv(cdfl);
        float zh = (cdfh >= 1.0f - 1e-7f) ? 1e30f : phi_inv(cdfh);
        sh_zl = zl; sh_zh = zh;
        sh_sLo = sigma * zl; sh_sHi = sigma * zh;
        sh_ok = 0;
    }
    __syncthreads();
    const float sigma = invT;

    // ------- fused stream: buckets A/W/B + race + stage, verify + retry -----
    unsigned long long mybest = 0ull;
    for (int attempt = 0; attempt < 32; ++attempt) {
        if (tid == 0) lcnt = 0u;
        __syncthreads();
        const float sLo = sh_sLo, sHi = sh_sHi;
        mybest = 0ull;
        float aacc = 0.0f, wacc = 0.0f, bacc = 0.0f;
        for (int v = tid; v < NV4; v += 2 * TPB) {
            int v1 = v + TPB;
            bool g1 = v1 < NV4;
            float4 x0 = l4[v];
            float4 u0 = u4[v];
            float4 x1 = l4[g1 ? v1 : v];
            float4 u1 = u4[g1 ? v1 : v];
            float xs0[4] = {x0.x, x0.y, x0.z, x0.w};
            float us0[4] = {u0.x, u0.y, u0.z, u0.w};
            float xs1[4] = {x1.x, x1.y, x1.z, x1.w};
            float us1[4] = {u1.x, u1.y, u1.z, u1.w};
            #pragma unroll
            for (int c = 0; c < 4; ++c) {
                float s = xs0[c] * invT;
                float q = qval(s);
                unsigned idx = (unsigned)(v * 4 + c);
                if (s >= sHi) {
                    unsigned long long key = race_key(s, us0[c], idx);
                    if (key > mybest) mybest = key;
                    aacc += q;
                } else if (s >= sLo) {
                    wacc += q;
                    unsigned pos = atomicAdd(&lcnt, 1u);
                    if (pos < GCAP) {
                        stage[pos] = ((unsigned long long)fenc(s) << 32) | (unsigned)(~idx);
                        stageU[pos] = __float_as_uint(us0[c]);
                    }
                } else {
                    bacc += q;
                }
            }
            #pragma unroll
            for (int c = 0; c < 4; ++c) {
                if (g1) {
                    float s = xs1[c] * invT;
                    float q = qval(s);
                    unsigned idx = (unsigned)(v1 * 4 + c);
                    if (s >= sHi) {
                        unsigned long long key = race_key(s, us1[c], idx);
                        if (key > mybest) mybest = key;
                        aacc += q;
                    } else if (s >= sLo) {
                        wacc += q;
                        unsigned pos = atomicAdd(&lcnt, 1u);
                        if (pos < GCAP) {
                            stage[pos] = ((unsigned long long)fenc(s) << 32) | (unsigned)(~idx);
                            stageU[pos] = __float_as_uint(us1[c]);
                        }
                    } else {
                        bacc += q;
                    }
                }
            }
        }
        // reduce A, W, B (B only needed on attempt 0 to form P = topp*Zq)
        #pragma unroll
        for (int o = 32; o > 0; o >>= 1) {
            aacc += __shfl_down(aacc, o, 64);
            wacc += __shfl_down(wacc, o, 64);
            bacc += __shfl_down(bacc, o, 64);
        }
        if ((tid & 63) == 0) wred[tid >> 6] = aacc;
        __syncthreads();
        if (tid == 0) {
            float sA = 0.0f;
            #pragma unroll
            for (int w = 0; w < TPB / 64; ++w) sA += wred[w];
            shA = sA;
        }
        __syncthreads();
        if ((tid & 63) == 0) wred[tid >> 6] = wacc;
        __syncthreads();
        float sW_bc = 0.0f;
        if (tid == 0) {
            #pragma unroll
            for (int w = 0; w < TPB / 64; ++w) sW_bc += wred[w];
        }
        __syncthreads();
        if ((tid & 63) == 0) wred[tid >> 6] = bacc;
        __syncthreads();
        if (tid == 0) {
            float sB = 0.0f;
            #pragma unroll
            for (int w = 0; w < TPB / 64; ++w) sB += wred[w];
            if (attempt == 0) shP = topp * (shA + sW_bc + sB);  // exact Zq bucket sum
            const float P = shP;
            unsigned n = lcnt;
            float A = shA;
            bool okhi = (A <= P);
            bool okn  = (n <= GCAP);
            bool oklo = (A + sW_bc > P) || (sh_zl <= -1e29f);
            if (okhi && okn && oklo) sh_ok = 1;
            else {
                float zl = sh_zl, zh = sh_zh;
                float width = zh - zl;
                if (!(width > 0.25f)) width = 0.25f;
                if (width > 8.0f) width = 8.0f;
                if (!okhi)      { zl = zh; zh = zh + 2.0f * width; }   // cut above window
                else if (!okn)  { zl = (zl > zh - 6.0f) ? 0.5f * (zl + zh) : (zh - 6.0f); }
                else            { zh = zl; zl = zl - 2.0f * width; }   // cut below window
                sh_zl = zl; sh_zh = zh;
                sh_sLo = sigma * zl; sh_sHi = sigma * zh;
            }
        }
        __syncthreads();
        if (sh_ok) break;
    }
    const float P = shP;

    // ---------------- select on window (proven round-11/12 machinery) -------
    if (tid == 0) {
        sh_gstar = -1; sh_tn = 0u; sh_kst = 0;
        sh_kmin = 0xFFFFFFFFu; sh_kmax = 0u;
    }
    for (int g = tid; g < NG; g += TPB) ms[g] = 0.0f;
    __syncthreads();

    unsigned n = lcnt; if (n > GCAP) n = GCAP;
    if (n > 0) {
        unsigned kmn = 0xFFFFFFFFu, kmx = 0u;
        for (unsigned p = tid; p < n; p += TPB) {
            unsigned k = (unsigned)(stage[p] >> 32);
            kmn = min(kmn, k); kmx = max(kmx, k);
        }
        atomicMin(&sh_kmin, kmn);
        atomicMax(&sh_kmax, kmx);
        __syncthreads();
        const unsigned kmin = sh_kmin;
        const unsigned span = sh_kmax - kmin;
        const int Lb = 32 - __clz(span);            // span==0 -> 0
        const int shft = (Lb > 11) ? (Lb - 11) : 0; // groups <= 2048

        for (unsigned p = tid; p < n; p += TPB) {
            unsigned key = (unsigned)(stage[p] >> 32);
            atomicAdd(&ms[(key - kmin) >> shft], qval(fdec(key)));
        }
        __syncthreads();

        for (int g = tid; g < NG; g += TPB) ssA[g] = ms[g];
        __syncthreads();
        float* src = ssA; float* dst = ssB;
        for (int d = 1; d < NG; d <<= 1) {
            for (int g = tid; g < NG; g += TPB)
                dst[g] = src[g] + ((g + d < NG) ? src[g + d] : 0.0f);
            __syncthreads();
            float* tm = src; src = dst; dst = tm;
        }
        const float A = shA;
        for (int g = tid; g < NG; g += TPB) {
            float SI  = src[g];
            float SI1 = (g + 1 < NG) ? src[g + 1] : 0.0f;
            if (A + SI > P && A + SI1 <= P) atomicMax(&sh_gstar, g);
        }
        __syncthreads();
        const int gstar = sh_gstar;
        if (tid == 0)
            sh_above = A + ((gstar >= 0 && gstar + 1 < NG) ? src[gstar + 1] : 0.0f);

        for (unsigned p = tid; p < n; p += TPB) {
            unsigned long long e = stage[p];
            unsigned key = (unsigned)(e >> 32);
            int g = (int)((key - kmin) >> shft);
            if (gstar < 0 || g > gstar) {
                unsigned idx = ~(unsigned)(e & 0xFFFFFFFFull);
                unsigned long long k2 =
                    race_key(fdec(key), __uint_as_float(stageU[p]), idx);
                if (k2 > mybest) mybest = k2;
            } else if (g == gstar) {
                unsigned t = atomicAdd(&sh_tn, 1u);
                if (t < TCAP) { tk[t] = e; tu[t] = stageU[p]; }
            }
        }
        __syncthreads();
        unsigned tn = sh_tn; if (tn > TCAP) tn = TCAP;
        if (gstar >= 0 && tn > 0u) {
            int N2 = 64; while (N2 < (int)tn) N2 <<= 1;
            for (int i = tid; i < N2; i += TPB)
                if (i >= (int)tn) { tk[i] = 0ull; tu[i] = 0u; }
            __syncthreads();
            for (int k = 2; k <= N2; k <<= 1) {
                for (int j2 = k >> 1; j2 > 0; j2 >>= 1) {
                    for (int i = tid; i < N2; i += TPB) {
                        int ixj = i ^ j2;
                        if (ixj > i) {
                            unsigned long long a = tk[i], b = tk[ixj];
                            if (((i & k) == 0) ? (a < b) : (a > b)) {
                                tk[i] = b; tk[ixj] = a;
                                unsigned ut = tu[i]; tu[i] = tu[ixj]; tu[ixj] = ut;
                            }
                        }
                    }
                    __syncthreads();
                }
            }
            for (int i = tid; i < N2; i += TPB)
                ssA[i] = (i < (int)tn) ? qval(fdec((unsigned)(tk[i] >> 32))) : 0.0f;
            __syncthreads();
            float* s1 = ssA; float* s2 = ssB;
            for (int d = 1; d < N2; d <<= 1) {
                for (int i = tid; i < N2; i += TPB)
                    s2[i] = s1[i] + ((i >= d) ? s1[i - d] : 0.0f);
                __syncthreads();
                float* tm = s1; s1 = s2; s2 = tm;
            }
            const float above = sh_above;
            for (int i = tid; i < (int)tn; i += TPB) {
                float excl = above + ((i == 0) ? 0.0f : s1[i - 1]);
                if (excl <= P) atomicMax(&sh_kst, i + 1);
            }
            __syncthreads();
            const int kst = sh_kst;
            for (int i = tid; i < kst; i += TPB) {
                unsigned idx = ~(unsigned)(tk[i] & 0xFFFFFFFFull);
                unsigned long long k2 =
                    race_key(fdec((unsigned)(tk[i] >> 32)), __uint_as_float(tu[i]), idx);
                if (k2 > mybest) mybest = k2;
            }
            __syncthreads();
        }
    }

    // final winner reduce
    #pragma unroll
    for (int o = 32; o > 0; o >>= 1) {
        unsigned long long other = __shfl_down(mybest, o, 64);
        if (other > mybest) mybest = other;
    }
    if ((tid & 63) == 0) red_b[tid >> 6] = mybest;
    __syncthreads();
    if (tid == 0) {
        unsigned long long m2 = red_b[0];
        #pragma unroll
        for (int w = 1; w < TPB / 64; ++w) if (red_b[w] > m2) m2 = red_b[w];
        out[row] = (int)(~(unsigned)(m2 & 0xFFFFFFFFull));
    }
}

extern "C" void kernel_launch(void* const* d_in, const int* in_sizes, int n_in,
                              void* d_out, int out_size, void* d_ws, size_t ws_size,
                              hipStream_t stream) {
    const float* logits = (const float*)d_in[0];
    const float* temps  = (const float*)d_in[1];
    const float* topps  = (const float*)d_in[2];
    const float* unoise = (const float*)d_in[3];
    int* out = (int*)d_out;
    hipLaunchKernelGGL(sampler_all, dim3(NROW), dim3(TPB), 0, stream,
                       logits, temps, topps, unoise, out);
}